// Round 9
// baseline (730.767 us; speedup 1.0000x reference)
//
#include <hip/hip_runtime.h>
#include <hip/hip_bf16.h>

typedef __attribute__((ext_vector_type(8))) short bf16x8;
typedef __attribute__((ext_vector_type(4))) float f32x4;

static constexpr int BB = 256;   // batch
static constexpr int TT = 33;    // time (input)
static constexpr int EE = 1024;  // embed
static constexpr int LL = 32;    // scan steps = T-1
static constexpr int NG = 4096;  // 4*E gate rows

static constexpr int BUF_SZ   = 24576;    // 16KB W + 8KB A per chunk buffer
static constexpr int A_OFF    = 16384;    // A area within a buffer
static constexpr int LDSG_OFF = 98304;    // 16KB gate-exchange (separate, no aliasing)
static constexpr int HH_OFF   = 114688;   // 2KB h tile
static constexpr int LDS_DYN  = 116736;

__device__ __forceinline__ short f2bf(float f) {
  unsigned u = __builtin_bit_cast(unsigned, f);
  u += 0x7fffu + ((u >> 16) & 1u);   // RNE
  return (short)(u >> 16);
}

__device__ __forceinline__ bf16x8 cvt8(f32x4 a, f32x4 b) {
  bf16x8 r;
  r[0] = f2bf(a[0]); r[1] = f2bf(a[1]); r[2] = f2bf(a[2]); r[3] = f2bf(a[3]);
  r[4] = f2bf(b[0]); r[5] = f2bf(b[1]); r[6] = f2bf(b[2]); r[7] = f2bf(b[3]);
  return r;
}

__device__ __forceinline__ float sigm(float x) { return 1.0f / (1.0f + __expf(-x)); }
__device__ __forceinline__ float tanh_f(float x) { return 1.0f - 2.0f / (__expf(2.0f * x) + 1.0f); }

// ---- prep: x fp32 -> bf16 [t][row][e]; c0 = x[:,1,:]; zero 256 flags
__global__ __launch_bounds__(256) void lstm_prep(
    const float* __restrict__ x, short* __restrict__ xbf, float* __restrict__ c_io,
    unsigned* __restrict__ flags)
{
  if (blockIdx.x == 0) flags[(size_t)threadIdx.x * 64] = 0;
  int gth = blockIdx.x * 256 + threadIdx.x;
  int eb  = gth & 127;
  int row = (gth >> 7) & 255;
  int t   = gth >> 15;
  const float* src = x + ((size_t)row * TT + t) * EE + (eb << 3);
  f32x4 lo = *(const f32x4*)src;
  f32x4 hi = *(const f32x4*)(src + 4);
  *(bf16x8*)(xbf + ((size_t)t * BB + row) * EE + (eb << 3)) = cvt8(lo, hi);
  if (t == 1) {
    float* cd = c_io + (size_t)row * EE + (eb << 3);
    *(f32x4*)cd = lo;
    *(f32x4*)(cd + 4) = hi;
  }
}

// ---- rec: 256 WGs x 512 thr, 114KB dynamic LDS, cooperative (fallback plain).
// FLAT chunk pipeline across steps: buffer = flatchunk&3 (4 bufs), stage 3 ahead,
// vmcnt(6) counted waits, ONE s_barrier per chunk (distance-4 restage is safe:
// the pre-compute barrier proves the buffer's previous compute retired).
// Next step's flag-free phase-A chunks stage during this step's tail -> the
// epilogue no longer drains the pipeline. Epilogue LDS is a separate area.
// h: rotating per-t buffers, sc1 publish, per-WG flag (proven round 8).
__global__ __launch_bounds__(512) void lstm_rec(
    const short* __restrict__ xbf,   // [32][256][1024] bf16
    const float* __restrict__ Wih,   // [32][4096][1024]
    const float* __restrict__ Whh,   // [32][4096][1024]
    short* __restrict__ hroll,       // [32][256][1024] bf16 rotating
    float* __restrict__ c_io,        // [256][1024] fp32 (d_out c region)
    float* __restrict__ h_out,       // [256][1024] fp32 (d_out h region)
    unsigned* __restrict__ flags)    // [256] slots, 64-uint spacing
{
  extern __shared__ __align__(16) char smem[];

  const int tid  = threadIdx.x;
  const int lane = tid & 63;
  const int wv   = tid >> 6;      // 0..7
  const int g    = wv & 3;        // gate
  const int hf   = wv >> 2;       // row half
  const int lr   = lane & 15;
  const int kg   = lane >> 4;

  const int wg     = blockIdx.x;        // 0..255
  const int xcd    = wg & 7;
  const int jj     = wg >> 3;
  const int rowgrp = jj & 3;            // 4 x 64 rows
  const int ehi    = jj >> 2;           // 0..7
  const int e0     = (xcd * 8 + ehi) << 4;
  const int row0   = rowgrp << 6;

  const int rowW  = g * 16 + lr;
  const int mw    = ((lr & 7) << 5) | ((lr & 8) << 1);
  const int ma    = (lr & 7) << 4;
  const int arow0 = hf * 32 + lr;

  // ---- hoisted per-thread staging constants
  size_t wsrc_off[2]; int wdst_off[2];
#pragma unroll
  for (int r = 0; r < 2; ++r) {
    int o = r * 8192 + wv * 1024 + lane * 16;
    int lrow = o >> 8;
    int mwr = ((lrow & 7) << 5) | ((lrow & 8) << 1);
    wsrc_off[r] = (size_t)((lrow >> 4) * EE + e0 + (lrow & 15)) * 4096 + ((o & 255) ^ mwr);
    wdst_off[r] = r * 8192 + wv * 1024;
  }
  size_t asrc_off; int adst_off;
  {
    int o = wv * 1024 + lane * 16;
    int lrow = o >> 7;
    asrc_off = (size_t)(row0 + lrow) * 2048 + ((o & 127) ^ ((lrow & 7) << 4));
    adst_off = A_OFF + wv * 1024;
  }

  const int rl0  = tid >> 4;
  const int ecol = e0 + (tid & 15);
  float c0r = c_io[(size_t)(row0 + rl0) * EE + ecol];
  float c1r = c_io[(size_t)(row0 + rl0 + 32) * EE + ecol];

  f32x4 acc0{}, acc1{};

  auto stageC = [&](int tt, int cc, int buf) {
    const int p  = cc >> 4;             // 0: x@Wih, 1: h@Whh
    const int k0 = (cc & 15) << 6;
    const char* Wt = (const char*)((p ? Whh : Wih) + (size_t)tt * NG * EE);
    const char* At = p ? (const char*)(hroll + (size_t)(tt - 1) * BB * EE)
                       : (const char*)(xbf + (size_t)tt * BB * EE);
    char* dst = smem + buf * BUF_SZ;
#pragma unroll
    for (int r = 0; r < 2; ++r)
      __builtin_amdgcn_global_load_lds(
          (const __attribute__((address_space(1))) unsigned int*)(Wt + wsrc_off[r] + (k0 << 2)),
          (__attribute__((address_space(3))) unsigned int*)(dst + wdst_off[r]), 16, 0, 0);
    __builtin_amdgcn_global_load_lds(
        (const __attribute__((address_space(1))) unsigned int*)(At + asrc_off + (k0 << 1)),
        (__attribute__((address_space(3))) unsigned int*)(dst + adst_off), 16, 0, 0);
  };

  auto compute = [&](int buf) {
    const char* Wb = smem + buf * BUF_SZ;
    const char* Ab = Wb + A_OFF;
#pragma unroll
    for (int kit = 0; kit < 2; ++kit) {
      int u5 = (kit * 4 + kg) << 5;
      f32x4 wlo = *(const f32x4*)(Wb + rowW * 256 + ((u5) ^ mw));
      f32x4 whi = *(const f32x4*)(Wb + rowW * 256 + ((u5 | 16) ^ mw));
      bf16x8 bfr = cvt8(wlo, whi);
      int u4 = ((kit * 4 + kg) << 4) ^ ma;
      bf16x8 a0 = *(const bf16x8*)(Ab + arow0 * 128 + u4);
      bf16x8 a1 = *(const bf16x8*)(Ab + (arow0 + 16) * 128 + u4);
      acc0 = __builtin_amdgcn_mfma_f32_16x16x32_bf16(a0, bfr, acc0, 0, 0, 0);
      acc1 = __builtin_amdgcn_mfma_f32_16x16x32_bf16(a1, bfr, acc1, 0, 0, 0);
    }
  };

  // prologue: stage flat chunks 0,1,2
  stageC(0, 0, 0);
  stageC(0, 1, 1);
  stageC(0, 2, 2);

  int fc = 0;   // flat chunk counter
  for (int t = 0; t < LL; ++t) {
    const int nch = t ? 32 : 16;
    for (int c = 0; c < nch; ++c, ++fc) {
      if (t == LL - 1 && c == nch - 1)      asm volatile("s_waitcnt vmcnt(0)" ::: "memory");
      else if (t == LL - 1 && c == nch - 2) asm volatile("s_waitcnt vmcnt(3)" ::: "memory");
      else                                   asm volatile("s_waitcnt vmcnt(6)" ::: "memory");
      __builtin_amdgcn_s_barrier();
      compute(fc & 3);

      if (t < LL - 1 || c + 3 < nch) {
        int sc = c + 3, st = t;
        if (sc >= nch) { sc -= nch; st = t + 1; }
        if (st == t && sc == 16) {           // gate first phase-B chunk on h[t-1]
          if (tid < 256) {
            while (__hip_atomic_load(flags + (size_t)tid * 64,
                                     __ATOMIC_RELAXED, __HIP_MEMORY_SCOPE_AGENT) < (unsigned)t)
              __builtin_amdgcn_s_sleep(1);
          }
          __builtin_amdgcn_s_barrier();
          __builtin_amdgcn_sched_barrier(0);
        }
        if (!(st > t && sc == 2))            // (t+1,2) deferred to epilogue
          stageC(st, sc, (fc + 3) & 3);
      }
    }

    // ---- epilogue (separate LDS area; no buffer aliasing)
    float* ldsg = (float*)(smem + LDSG_OFF);
    short* hh   = (short*)(smem + HH_OFF);
#pragma unroll
    for (int j = 0; j < 4; ++j) {
      ldsg[(g * 64 + hf * 32 + (kg << 2) + j) * 16 + lr] = acc0[j];
      ldsg[(g * 64 + hf * 32 + 16 + (kg << 2) + j) * 16 + lr] = acc1[j];
    }
    acc0 = f32x4{}; acc1 = f32x4{};
    asm volatile("s_waitcnt lgkmcnt(0)" ::: "memory");
    __builtin_amdgcn_s_barrier();

    {
      int el = tid & 15;
      float gi0 = ldsg[(0 * 64 + rl0) * 16 + el];
      float gf0 = ldsg[(1 * 64 + rl0) * 16 + el];
      float gg0 = ldsg[(2 * 64 + rl0) * 16 + el];
      float go0 = ldsg[(3 * 64 + rl0) * 16 + el];
      float gi1 = ldsg[(0 * 64 + rl0 + 32) * 16 + el];
      float gf1 = ldsg[(1 * 64 + rl0 + 32) * 16 + el];
      float gg1 = ldsg[(2 * 64 + rl0 + 32) * 16 + el];
      float go1 = ldsg[(3 * 64 + rl0 + 32) * 16 + el];

      c0r = sigm(gf0) * c0r + sigm(gi0) * tanh_f(gg0);
      float h0n = sigm(go0) * tanh_f(c0r);
      c1r = sigm(gf1) * c1r + sigm(gi1) * tanh_f(gg1);
      float h1n = sigm(go1) * tanh_f(c1r);

      hh[rl0 * 16 + el] = f2bf(h0n);
      hh[(rl0 + 32) * 16 + el] = f2bf(h1n);

      if (t == LL - 1) {
        size_t o0 = (size_t)(row0 + rl0) * EE + ecol;
        size_t o1 = (size_t)(row0 + rl0 + 32) * EE + ecol;
        h_out[o0] = h0n; c_io[o0] = c0r;
        h_out[o1] = h1n; c_io[o1] = c1r;
      }
    }
    asm volatile("s_waitcnt lgkmcnt(0)" ::: "memory");
    __builtin_amdgcn_s_barrier();

    if (t < LL - 1) {
      // publish h[t] (sc1 -> L3), then deferred stage, then in-order vmcnt proof
      if (tid < 256) {
        int r = tid >> 2, q = tid & 3;
        unsigned long long v = *(const unsigned long long*)((char*)hh + r * 32 + q * 8);
        __hip_atomic_store(
            (unsigned long long*)((char*)hroll + ((size_t)t * BB + row0 + r) * 2048 + (size_t)e0 * 2 + q * 8),
            v, __ATOMIC_RELAXED, __HIP_MEMORY_SCOPE_AGENT);
      }
      stageC(t + 1, 2, (fc + 2) & 3);
      asm volatile("s_waitcnt vmcnt(3)" ::: "memory");   // in-order: publish store retired
      __builtin_amdgcn_s_barrier();                      // ...for ALL waves
      if (tid == 0)
        __hip_atomic_store(flags + (size_t)wg * 64, (unsigned)(t + 1),
                           __ATOMIC_RELAXED, __HIP_MEMORY_SCOPE_AGENT);
    }
  }
}

__global__ __launch_bounds__(256) void lstm_loss_part(
    const float* __restrict__ h, const float* __restrict__ tgt, float* __restrict__ partials)
{
  __shared__ float lds[4];
  int tid = threadIdx.x;
  float s = 0.f;
  int base = blockIdx.x * 1024 + tid;
#pragma unroll
  for (int q = 0; q < 4; ++q) {
    int idx = base + (q << 8);
    s += fabsf(h[idx] - tgt[idx]);
  }
#pragma unroll
  for (int off = 32; off > 0; off >>= 1) s += __shfl_down(s, off, 64);
  if ((tid & 63) == 0) lds[tid >> 6] = s;
  __syncthreads();
  if (tid == 0) partials[blockIdx.x] = lds[0] + lds[1] + lds[2] + lds[3];
}

__global__ __launch_bounds__(256) void lstm_loss_fin(
    const float* __restrict__ partials, float* __restrict__ out)
{
  __shared__ float lds[4];
  int tid = threadIdx.x;
  float s = partials[tid];
#pragma unroll
  for (int off = 32; off > 0; off >>= 1) s += __shfl_down(s, off, 64);
  if ((tid & 63) == 0) lds[tid >> 6] = s;
  __syncthreads();
  if (tid == 0) out[0] = (lds[0] + lds[1] + lds[2] + lds[3]) * (1.0f / 262144.0f);
}

extern "C" void kernel_launch(void* const* d_in, const int* in_sizes, int n_in,
                              void* d_out, int out_size, void* d_ws, size_t ws_size,
                              hipStream_t stream) {
  const float* x   = (const float*)d_in[0];
  const float* tgt = (const float*)d_in[1];
  const float* Wih = (const float*)d_in[2];
  const float* Whh = (const float*)d_in[3];

  float* out   = (float*)d_out;
  float* h_out = out + 1;                 // [256*1024]
  float* c_io  = out + 1 + BB * EE;       // [256*1024]

  // ws: xbf (16.8MB) | hroll 32 slots (16.8MB) | partials (1KB) | flags (64KB)
  short* xbf      = (short*)d_ws;
  short* hroll    = (short*)((char*)xbf + (size_t)LL * BB * EE * 2);
  float* partials = (float*)((char*)hroll + (size_t)LL * BB * EE * 2);
  unsigned* flags = (unsigned*)((char*)partials + 1024);

  static bool attr_done = false;
  if (!attr_done) {
    hipFuncSetAttribute((const void*)lstm_rec,
                        hipFuncAttributeMaxDynamicSharedMemorySize, LDS_DYN);
    attr_done = true;
  }

  lstm_prep<<<4096, 256, 0, stream>>>(x, xbf, c_io, flags);

  {
    const short* xbfA = xbf; const float* WihA = Wih; const float* WhhA = Whh;
    short* hrollA = hroll; float* cA = c_io; float* hA = h_out; unsigned* flagsA = flags;
    void* args[] = {&xbfA, &WihA, &WhhA, &hrollA, &cA, &hA, &flagsA};
    hipError_t e = hipLaunchCooperativeKernel((void*)lstm_rec, dim3(256), dim3(512),
                                              args, LDS_DYN, stream);
    if (e != hipSuccess)   // insurance vs silent coop rejection (round 3/4 lesson)
      lstm_rec<<<256, 512, LDS_DYN, stream>>>(xbf, Wih, Whh, hroll, c_io, h_out, flags);
  }

  lstm_loss_part<<<256, 256, 0, stream>>>(h_out, tgt, partials);
  lstm_loss_fin<<<1, 256, 0, stream>>>(partials, out);
}